// Round 8
// baseline (366.077 us; speedup 1.0000x reference)
//
#include <hip/hip_runtime.h>
#include <stdint.h>

// out[b,c] = sum_{k<256} batchs[b,k] * label2embed[c,k]
// A = batchs [16384, 256] fp32, Bm = label2embed [4096, 256] fp32, out [16384,4096] fp32.
// GEMM-BT, K=256. Write floor: 268 MB @ 6.4 TB/s (measured fill rate) = 42 us.
//
// Session ledger:
//  R0: fill(~167 ws poison) + [out-poison ~42?] + cvt(6) + gemm(~82-124?) = 297.
//  R1: cvt fused into gemm -> 50x VALU blowup (+55). REVERTED.
//  R2: no-LDS direct fragments -> +82. REVERTED.
//  R3: f32x4 epilogue -> NEUTRAL. R4: counted-vmcnt pipeline -> NEUTRAL.
//  R5: nt stores -> +17. R6: 128x64/5-blocks-CU -> +13. R7: LDS-transposed
//      full-line epilogue -> NEUTRAL. EIGHT levers, eight nulls on the gemm.
//  R8 (this): MEASUREMENT ROUND. The invariance suggests the gemm may ALREADY be
//      near the write floor, with the residual being harness poison + dispatch gaps
//      (never directly measured: gemm never appears in top-5). Launch the idempotent
//      gemm TWICE: dur_new - dur_old = true gemm duration.
//      Delta ~45-60 -> gemm at floor -> declare structural ceiling next round.
//      Delta ~85-125 -> real headroom -> attack DRAM write granularity (wide tiles).
#define MDIM 16384
#define NDIM 4096
#define KDIM 256

#define BM 128
#define BN 128
#define BK 32
#define KSTEPS (KDIM / BK)   // 8

typedef __attribute__((ext_vector_type(8))) short bf16x8;
typedef __attribute__((ext_vector_type(4))) float f32x4;

__device__ __forceinline__ unsigned short f2bf_rne(float f) {
    union { float f; uint32_t u; } v; v.f = f;
    uint32_t u = v.u;
    u += 0x7fffu + ((u >> 16) & 1u);   // round-to-nearest-even (finite inputs)
    return (unsigned short)(u >> 16);
}

// Pass 1: fp32 -> bf16 for both inputs, into workspace. 8 elems/thread, 16B stores.
__global__ __launch_bounds__(256) void cvt_kernel(const float* __restrict__ a,
                                                  const float* __restrict__ b,
                                                  unsigned short* __restrict__ wa,
                                                  unsigned short* __restrict__ wb) {
    const int64_t nA = (int64_t)MDIM * KDIM;
    int64_t i = ((int64_t)blockIdx.x * 256 + threadIdx.x) * 8;
    const float* src; unsigned short* dst; int64_t off;
    if (i < nA) { src = a; dst = wa; off = i; }
    else        { src = b; dst = wb; off = i - nA; }
    float4 f0 = *(const float4*)(src + off);
    float4 f1 = *(const float4*)(src + off + 4);
    union { unsigned short h[8]; int4 v; } o;
    o.h[0] = f2bf_rne(f0.x); o.h[1] = f2bf_rne(f0.y);
    o.h[2] = f2bf_rne(f0.z); o.h[3] = f2bf_rne(f0.w);
    o.h[4] = f2bf_rne(f1.x); o.h[5] = f2bf_rne(f1.y);
    o.h[6] = f2bf_rne(f1.z); o.h[7] = f2bf_rne(f1.w);
    *(int4*)(dst + off) = o.v;
}

// Stage one 128x32 bf16 tile of A and B into LDS via width-16 global_load_lds.
// chunk ch in [0,512): row = ch>>2, col = (ch&3)*8; LDS byte off = ch*16.
__device__ __forceinline__ void stage_tiles(const unsigned short* __restrict__ Ab,
                                            const unsigned short* __restrict__ Bb,
                                            unsigned short* sA, unsigned short* sB,
                                            int tid, int k0) {
#pragma unroll
    for (int c = 0; c < 2; ++c) {
        int ch  = tid + c * 256;
        int row = ch >> 2;
        int col = (ch & 3) << 3;
        __builtin_amdgcn_global_load_lds(
            (const __attribute__((address_space(1))) void*)(Ab + (size_t)row * KDIM + k0 + col),
            (__attribute__((address_space(3))) void*)(sA + ch * 8), 16, 0, 0);
        __builtin_amdgcn_global_load_lds(
            (const __attribute__((address_space(1))) void*)(Bb + (size_t)row * KDIM + k0 + col),
            (__attribute__((address_space(3))) void*)(sB + ch * 8), 16, 0, 0);
    }
}

// Pass 2: bf16 MFMA GEMM-BT, R3-champion structure (best measured: 297.0 us total).
// 128x128 tile/block, 4 waves, 64x64 quadrant each, BK=32, dbuf LDS, 1 barrier/step.
__global__ __launch_bounds__(256, 4) void gemm_bt(const unsigned short* __restrict__ A,
                                                  const unsigned short* __restrict__ Bm,
                                                  float* __restrict__ out) {
    __shared__ __align__(16) unsigned short sA[2][BM * BK];  // 2 x 8 KiB
    __shared__ __align__(16) unsigned short sB[2][BN * BK];  // 2 x 8 KiB

    const int tid  = threadIdx.x;
    const int lane = tid & 63;
    const int wave = tid >> 6;
    const int wm   = wave >> 1;
    const int wn   = wave & 1;
    const int quad = lane >> 4;
    const int r16  = lane & 15;

    // XCD-aware swizzle: each XCD owns a band of 16 bm's; bn sweeps fastest ->
    // per-XCD set = A band (1 MB) + full B (2 MB) = 3 MB < 4 MB XCD L2.
    const int id  = blockIdx.x;
    const int xcd = id & 7;
    const int g   = id >> 3;                // 0..511
    const int bm  = (xcd << 4) | (g >> 5);  // 0..127
    const int bn  = g & 31;                 // 0..31

    const unsigned short* Ab = A  + (size_t)bm * BM * KDIM;
    const unsigned short* Bb = Bm + (size_t)bn * BN * KDIM;

    f32x4 acc[4][4] = {};

    stage_tiles(Ab, Bb, sA[0], sB[0], tid, 0);

#pragma unroll
    for (int step = 0; step < KSTEPS; ++step) {
        __syncthreads();  // drains vmcnt for buf[step&1]; WAR-protects buf[(step+1)&1]
        if (step + 1 < KSTEPS)
            stage_tiles(Ab, Bb, sA[(step + 1) & 1], sB[(step + 1) & 1], tid, (step + 1) * BK);

        const unsigned short* cA = sA[step & 1];
        const unsigned short* cB = sB[step & 1];

        // Fragment: X[row = lane&15][k = quad*8 + j]  (one ds_read_b128 each)
        bf16x8 af[4], bfr[4];
#pragma unroll
        for (int i = 0; i < 4; ++i)
            af[i] = *(const bf16x8*)(cA + ((wm * 64 + i * 16 + r16) * BK + quad * 8));
#pragma unroll
        for (int j = 0; j < 4; ++j)
            bfr[j] = *(const bf16x8*)(cB + ((wn * 64 + j * 16 + r16) * BK + quad * 8));

        // SWAPPED operands (validated R1-R7): D = mfma(bfr, af) ->
        // lane holds out[row = wm*64+i*16+r16][col = wn*64+j*16+quad*4 .. +3].
#pragma unroll
        for (int i = 0; i < 4; ++i)
#pragma unroll
            for (int j = 0; j < 4; ++j)
                acc[i][j] = __builtin_amdgcn_mfma_f32_16x16x32_bf16(bfr[j], af[i], acc[i][j], 0, 0, 0);
    }

    // Epilogue: 16 dwordx4 stores/lane; per instruction 16 rows x 64B contiguous.
#pragma unroll
    for (int i = 0; i < 4; ++i) {
        size_t row = (size_t)bm * BM + wm * 64 + i * 16 + r16;
#pragma unroll
        for (int j = 0; j < 4; ++j) {
            int col = bn * BN + wn * 64 + j * 16 + quad * 4;
            *(f32x4*)(out + row * NDIM + col) = acc[i][j];
        }
    }
}

// Fallback (only if ws too small): fp32 dot, one thread per output.
__global__ __launch_bounds__(256) void naive_f32(const float* __restrict__ a,
                                                 const float* __restrict__ b,
                                                 float* __restrict__ out) {
    int64_t idx = (int64_t)blockIdx.x * 256 + threadIdx.x;
    int c = (int)(idx & (NDIM - 1));
    int r = (int)(idx >> 12);
    const float4* ap = (const float4*)(a + (size_t)r * KDIM);
    const float4* bp = (const float4*)(b + (size_t)c * KDIM);
    float s = 0.f;
#pragma unroll 8
    for (int k = 0; k < KDIM / 4; ++k) {
        float4 x = ap[k], y = bp[k];
        s += x.x * y.x + x.y * y.y + x.z * y.z + x.w * y.w;
    }
    out[idx] = s;
}

extern "C" void kernel_launch(void* const* d_in, const int* in_sizes, int n_in,
                              void* d_out, int out_size, void* d_ws, size_t ws_size,
                              hipStream_t stream) {
    const float* a = (const float*)d_in[0];   // batchs  [16384, 2, 128]
    const float* b = (const float*)d_in[1];   // label2embed [4096, 2, 128]
    float* out = (float*)d_out;               // [16384, 4096]

    const size_t need = ((size_t)MDIM + NDIM) * KDIM * sizeof(unsigned short); // 10.5 MB
    if (d_ws != nullptr && ws_size >= need) {
        unsigned short* wa = (unsigned short*)d_ws;
        unsigned short* wb = wa + (size_t)MDIM * KDIM;
        const int64_t nvec = ((int64_t)MDIM + NDIM) * KDIM / 8;  // 655,360
        cvt_kernel<<<(int)(nvec / 256), 256, 0, stream>>>(a, b, wa, wb);       // 2560 blocks
        gemm_bt<<<(MDIM / BM) * (NDIM / BN), 256, 0, stream>>>(wa, wb, out);   // 4096 blocks
        // R8 MEASUREMENT: second, idempotent launch. dur_us delta == true gemm duration.
        gemm_bt<<<(MDIM / BM) * (NDIM / BN), 256, 0, stream>>>(wa, wb, out);
    } else {
        naive_f32<<<(int64_t)MDIM * NDIM / 256, 256, 0, stream>>>(a, b, out);
    }
}